// Round 1
// baseline (376.521 us; speedup 1.0000x reference)
//
#include <hip/hip_runtime.h>
#include <stdint.h>
#include <math.h>

typedef short short8 __attribute__((ext_vector_type(8)));
typedef float f32x4 __attribute__((ext_vector_type(4)));

// Problem constants
#define S_LEN   2048
#define DMODEL  2048
#define NHEADS  16
#define HDIM    128
#define NBATCH  2
#define BHTOT   32      // NBATCH*NHEADS
#define MROWS   4096    // NBATCH*S_LEN

// Workspace byte offsets (total ~89 MB)
#define XB_OFF   ((size_t)0)          // 4096*2048 bf16 = 16MB   (x bf16; reused as attn-output O)
#define WQ_OFF   ((size_t)16777216)   // 2048*2048 bf16 = 8MB    (Wq bf16; reused for Wo bf16)
#define WK_OFF   ((size_t)25165824)
#define WV_OFF   ((size_t)33554432)
#define Q_OFF    ((size_t)41943040)   // (bh,s,d) bf16 16MB
#define K_OFF    ((size_t)58720256)   // (bh,s,d) bf16 16MB
#define VT_OFF   ((size_t)75497472)   // (bh,d,s) bf16 16MB  (V pre-transposed)
#define COS_OFF  ((size_t)92274688)   // 2048*64 f32
#define SIN_OFF  ((size_t)92798976)   // 2048*64 f32

__device__ __forceinline__ unsigned short f2bf(float f) {
  unsigned int u = __float_as_uint(f);
  unsigned int r = (u + 0x7FFFu + ((u >> 16) & 1u)) >> 16;  // RTNE
  return (unsigned short)r;
}
__device__ __forceinline__ float bf2f(unsigned short b) {
  return __uint_as_float(((unsigned int)b) << 16);
}

// ---------------- fp32 -> bf16 convert (vectorized) ----------------
__global__ __launch_bounds__(256) void k_cvt(const float* __restrict__ src,
                                             unsigned short* __restrict__ dst, int n4) {
  int i = blockIdx.x * 256 + threadIdx.x;
  if (i >= n4) return;
  float4 v = ((const float4*)src)[i];
  ushort4 o;
  o.x = f2bf(v.x); o.y = f2bf(v.y); o.z = f2bf(v.z); o.w = f2bf(v.w);
  ((ushort4*)dst)[i] = o;
}

// ---------------- RoPE cos/sin table: [s][j], j<64 ----------------
__global__ __launch_bounds__(256) void k_rope_table(float* __restrict__ ct,
                                                    float* __restrict__ st) {
  int i = blockIdx.x * 256 + threadIdx.x;   // 2048*64 total
  if (i >= S_LEN * 64) return;
  int s = i >> 6, j = i & 63;
  // inv_freq = theta^(-2j/128) = exp(-2j/128 * ln(10000))
  float inv = expf(-(float)(2 * j) * (9.210340371976184f / 128.0f));
  float ang = (float)s * inv;
  ct[i] = cosf(ang);
  st[i] = sinf(ang);
}

// ---------------- in-place RoPE on (bh, s, 128) bf16 ----------------
// shift=3: 8 chunk-slots/row (rope pairs c<4 + scaled passthrough); shift=2: rope pairs only
__global__ __launch_bounds__(256) void k_rope(unsigned short* __restrict__ t,
                                              const float* __restrict__ ct,
                                              const float* __restrict__ st,
                                              float scale, int shift) {
  int id = blockIdx.x * 256 + threadIdx.x;
  int row = id >> shift;               // bh*2048 + s
  int c = id & ((1 << shift) - 1);
  int s = row & (S_LEN - 1);
  unsigned short* base = t + (size_t)row * HDIM;
  if (c < 4) {
    short8 v1 = *(short8*)(base + c * 8);
    short8 v2 = *(short8*)(base + c * 8 + 32);
    int j0 = c * 8;
    const float* cb = ct + s * 64;
    const float* sb = st + s * 64;
    short8 o1, o2;
#pragma unroll
    for (int i = 0; i < 8; i++) {
      float x1 = bf2f((unsigned short)v1[i]);
      float x2 = bf2f((unsigned short)v2[i]);
      float c1 = cb[j0 + i],      s1 = sb[j0 + i];
      float c2 = cb[j0 + 32 + i], s2 = sb[j0 + 32 + i];
      o1[i] = (short)f2bf((x1 * c1 - x2 * s1) * scale);
      o2[i] = (short)f2bf((x2 * c2 + x1 * s2) * scale);
    }
    *(short8*)(base + c * 8) = o1;
    *(short8*)(base + c * 8 + 32) = o2;
  } else {
    int cc = 8 + (c - 4) * 2;   // passthrough chunks 8..15, scaled (Q only)
    short8 v1 = *(short8*)(base + cc * 8);
    short8 v2 = *(short8*)(base + cc * 8 + 8);
    short8 o1, o2;
#pragma unroll
    for (int i = 0; i < 8; i++) {
      o1[i] = (short)f2bf(bf2f((unsigned short)v1[i]) * scale);
      o2[i] = (short)f2bf(bf2f((unsigned short)v2[i]) * scale);
    }
    *(short8*)(base + cc * 8) = o1;
    *(short8*)(base + cc * 8 + 8) = o2;
  }
}

// ---------------- fused QKV projection GEMM ----------------
// C[m][e] = sum_k X[m][k] * W[e][k] + bias[e];  Q/K -> (bh,s,d), V -> (bh,d,s)
__global__ __launch_bounds__(256) void k_gemm_qkv(
    const unsigned short* __restrict__ xb,
    const unsigned short* __restrict__ wqb, const unsigned short* __restrict__ wkb,
    const unsigned short* __restrict__ wvb,
    const float* __restrict__ bq, const float* __restrict__ bk, const float* __restrict__ bv,
    unsigned short* __restrict__ qr, unsigned short* __restrict__ kr,
    unsigned short* __restrict__ vt) {
  __shared__ unsigned short As[128][72];   // +8 pad -> frag reads 2-way (free)
  __shared__ unsigned short Bs[128][72];
  int m0 = blockIdx.x * 128;
  int n0g = blockIdx.y * 128;              // 0..6143
  int wsel = n0g >> 11;                    // 0=Q 1=K 2=V
  int nw0 = n0g & (DMODEL - 1);
  const unsigned short* W = (wsel == 0) ? wqb : (wsel == 1 ? wkb : wvb);
  const float* bias = (wsel == 0) ? bq : (wsel == 1 ? bk : bv);
  int tid = threadIdx.x, lane = tid & 63, wid = tid >> 6;
  int wr = wid >> 1, wc = wid & 1;
  int lq = lane & 15, lk = lane >> 4;
  int r0 = tid >> 3, c8 = tid & 7;

  f32x4 acc[4][4];
#pragma unroll
  for (int m = 0; m < 4; m++)
#pragma unroll
    for (int n = 0; n < 4; n++) { acc[m][n][0]=0.f; acc[m][n][1]=0.f; acc[m][n][2]=0.f; acc[m][n][3]=0.f; }

  for (int k0 = 0; k0 < DMODEL; k0 += 64) {
    int4 ta[4], tb[4];
#pragma unroll
    for (int i = 0; i < 4; i++) {
      int row = i * 32 + r0;
      ta[i] = *(const int4*)(xb + (size_t)(m0 + row) * DMODEL + k0 + c8 * 8);
      tb[i] = *(const int4*)(W  + (size_t)(nw0 + row) * DMODEL + k0 + c8 * 8);
    }
#pragma unroll
    for (int i = 0; i < 4; i++) {
      int row = i * 32 + r0;
      *(int4*)&As[row][c8 * 8] = ta[i];
      *(int4*)&Bs[row][c8 * 8] = tb[i];
    }
    __syncthreads();
#pragma unroll
    for (int kk = 0; kk < 2; kk++) {
      short8 af[4], bfr[4];
#pragma unroll
      for (int m = 0; m < 4; m++)
        af[m] = *(const short8*)&As[wr * 64 + m * 16 + lq][kk * 32 + lk * 8];
#pragma unroll
      for (int n = 0; n < 4; n++)
        bfr[n] = *(const short8*)&Bs[wc * 64 + n * 16 + lq][kk * 32 + lk * 8];
#pragma unroll
      for (int m = 0; m < 4; m++)
#pragma unroll
        for (int n = 0; n < 4; n++)
          acc[m][n] = __builtin_amdgcn_mfma_f32_16x16x32_bf16(af[m], bfr[n], acc[m][n], 0, 0, 0);
    }
    __syncthreads();
  }

  // epilogue: bias + layout-transform stores
#pragma unroll
  for (int n = 0; n < 4; n++) {
    int el = nw0 + wc * 64 + n * 16 + lq;   // feature index within selected weight
    float bi = bias[el];
    int hh = el >> 7, dd = el & 127;
#pragma unroll
    for (int m = 0; m < 4; m++) {
      int sg = m0 + wr * 64 + m * 16 + lk * 4;  // global row (b*2048+s), base of 4
      int b = sg >> 11, ss = sg & (S_LEN - 1);
      if (wsel < 2) {
        unsigned short* dst = (wsel == 0 ? qr : kr) +
                              ((size_t)(b * NHEADS + hh) * S_LEN + ss) * HDIM + dd;
#pragma unroll
        for (int r = 0; r < 4; r++) dst[(size_t)r * HDIM] = f2bf(acc[m][n][r] + bi);
      } else {
        ushort4 o;
        o.x = f2bf(acc[m][n][0] + bi); o.y = f2bf(acc[m][n][1] + bi);
        o.z = f2bf(acc[m][n][2] + bi); o.w = f2bf(acc[m][n][3] + bi);
        *(ushort4*)(vt + ((size_t)(b * NHEADS + hh) * HDIM + dd) * S_LEN + ss) = o;
      }
    }
  }
}

// ---------------- causal flash attention ----------------
// Q pre-scaled by 1/sqrt(128). grid = (bh=32, qtile=32), 4 waves x 16 q-rows.
__global__ __launch_bounds__(256) void k_attn(
    const unsigned short* __restrict__ qr, const unsigned short* __restrict__ kr,
    const unsigned short* __restrict__ vt, unsigned short* __restrict__ ob) {
  __shared__ unsigned short Ks[64][136];    // kv x d (+8 pad)
  __shared__ unsigned short Vs[128][72];    // d x kv (+8 pad)
  __shared__ unsigned short Ps[4][16][72];  // per-wave P round-trip
  int bh = blockIdx.x, qt = blockIdx.y;
  int b = bh >> 4, h = bh & 15;
  int q0 = qt * 64;
  int tid = threadIdx.x, lane = tid & 63, w = tid >> 6;
  int lq = lane & 15, lk = lane >> 4;

  // Q fragments (registers)
  const unsigned short* qbase = qr + ((size_t)bh * S_LEN + q0 + w * 16 + lq) * HDIM + lk * 8;
  short8 qf[4];
#pragma unroll
  for (int ks = 0; ks < 4; ks++) qf[ks] = *(const short8*)(qbase + ks * 32);

  f32x4 acco[8];
#pragma unroll
  for (int nd = 0; nd < 8; nd++) { acco[nd][0]=0.f; acco[nd][1]=0.f; acco[nd][2]=0.f; acco[nd][3]=0.f; }
  float rm[4], rs[4];
#pragma unroll
  for (int r = 0; r < 4; r++) { rm[r] = -3.0e38f; rs[r] = 0.f; }

  for (int t = 0; t <= qt; t++) {
    int kv0 = t * 64;
    // stage K tile (64x128) and Vt tile (128x64)
#pragma unroll
    for (int i = 0; i < 4; i++) {
      int row = i * 16 + (tid >> 4), col = (tid & 15) * 8;
      *(int4*)&Ks[row][col] =
          *(const int4*)(kr + ((size_t)bh * S_LEN + kv0 + row) * HDIM + col);
    }
#pragma unroll
    for (int i = 0; i < 4; i++) {
      int row = i * 32 + (tid >> 3), col = (tid & 7) * 8;
      *(int4*)&Vs[row][col] =
          *(const int4*)(vt + ((size_t)bh * HDIM + row) * S_LEN + kv0 + col);
    }
    __syncthreads();

    // S = Q K^T (16x64 per wave)
    f32x4 sacc[4];
#pragma unroll
    for (int n = 0; n < 4; n++) { sacc[n][0]=0.f; sacc[n][1]=0.f; sacc[n][2]=0.f; sacc[n][3]=0.f; }
#pragma unroll
    for (int ks = 0; ks < 4; ks++) {
#pragma unroll
      for (int n = 0; n < 4; n++) {
        short8 kf = *(const short8*)&Ks[n * 16 + lq][ks * 32 + lk * 8];
        sacc[n] = __builtin_amdgcn_mfma_f32_16x16x32_bf16(qf[ks], kf, sacc[n], 0, 0, 0);
      }
    }
    // causal mask on diagonal tile
    if (t == qt) {
#pragma unroll
      for (int n = 0; n < 4; n++)
#pragma unroll
        for (int r = 0; r < 4; r++) {
          int qrow = q0 + w * 16 + lk * 4 + r;
          int kvc = kv0 + n * 16 + lq;
          if (kvc > qrow) sacc[n][r] = -3.0e38f;
        }
    }
    // online softmax (row r lives in 16-lane group lk across regs n)
    float pscale[4];
#pragma unroll
    for (int r = 0; r < 4; r++) {
      float mx = fmaxf(fmaxf(sacc[0][r], sacc[1][r]), fmaxf(sacc[2][r], sacc[3][r]));
      mx = fmaxf(mx, __shfl_xor(mx, 1, 64));
      mx = fmaxf(mx, __shfl_xor(mx, 2, 64));
      mx = fmaxf(mx, __shfl_xor(mx, 4, 64));
      mx = fmaxf(mx, __shfl_xor(mx, 8, 64));
      float mnew = fmaxf(rm[r], mx);
      float corr = __expf(rm[r] - mnew);
      rm[r] = mnew;
      float psum = 0.f;
#pragma unroll
      for (int n = 0; n < 4; n++) {
        float p = __expf(sacc[n][r] - mnew);
        sacc[n][r] = p;
        psum += p;
      }
      psum += __shfl_xor(psum, 1, 64);
      psum += __shfl_xor(psum, 2, 64);
      psum += __shfl_xor(psum, 4, 64);
      psum += __shfl_xor(psum, 8, 64);
      rs[r] = rs[r] * corr + psum;
      pscale[r] = corr;
    }
#pragma unroll
    for (int nd = 0; nd < 8; nd++)
#pragma unroll
      for (int r = 0; r < 4; r++) acco[nd][r] *= pscale[r];

    // P -> bf16 -> LDS (accumulator layout -> A-frag layout)
#pragma unroll
    for (int n = 0; n < 4; n++)
#pragma unroll
      for (int r = 0; r < 4; r++)
        Ps[w][lk * 4 + r][n * 16 + lq] = f2bf(sacc[n][r]);

    // PV: O += P @ V
#pragma unroll
    for (int ks = 0; ks < 2; ks++) {
      short8 pa = *(const short8*)&Ps[w][lq][ks * 32 + lk * 8];
#pragma unroll
      for (int nd = 0; nd < 8; nd++) {
        short8 vf = *(const short8*)&Vs[nd * 16 + lq][ks * 32 + lk * 8];
        acco[nd] = __builtin_amdgcn_mfma_f32_16x16x32_bf16(pa, vf, acco[nd], 0, 0, 0);
      }
    }
    __syncthreads();
  }

  // normalize + store O as (b, s, e) bf16
#pragma unroll
  for (int r = 0; r < 4; r++) {
    float inv = 1.0f / rs[r];
    int srow = q0 + w * 16 + lk * 4 + r;
    unsigned short* dst = ob + ((size_t)b * S_LEN + srow) * DMODEL + h * HDIM;
#pragma unroll
    for (int nd = 0; nd < 8; nd++) dst[nd * 16 + lq] = f2bf(acco[nd][r] * inv);
  }
}

// ---------------- output projection GEMM (fp32 out) ----------------
__global__ __launch_bounds__(256) void k_gemm_out(
    const unsigned short* __restrict__ ob, const unsigned short* __restrict__ wob,
    const float* __restrict__ bo, float* __restrict__ out) {
  __shared__ unsigned short As[128][72];
  __shared__ unsigned short Bs[128][72];
  int m0 = blockIdx.x * 128, n0 = blockIdx.y * 128;
  int tid = threadIdx.x, lane = tid & 63, wid = tid >> 6;
  int wr = wid >> 1, wc = wid & 1;
  int lq = lane & 15, lk = lane >> 4;
  int r0 = tid >> 3, c8 = tid & 7;

  f32x4 acc[4][4];
#pragma unroll
  for (int m = 0; m < 4; m++)
#pragma unroll
    for (int n = 0; n < 4; n++) { acc[m][n][0]=0.f; acc[m][n][1]=0.f; acc[m][n][2]=0.f; acc[m][n][3]=0.f; }

  for (int k0 = 0; k0 < DMODEL; k0 += 64) {
    int4 ta[4], tb[4];
#pragma unroll
    for (int i = 0; i < 4; i++) {
      int row = i * 32 + r0;
      ta[i] = *(const int4*)(ob  + (size_t)(m0 + row) * DMODEL + k0 + c8 * 8);
      tb[i] = *(const int4*)(wob + (size_t)(n0 + row) * DMODEL + k0 + c8 * 8);
    }
#pragma unroll
    for (int i = 0; i < 4; i++) {
      int row = i * 32 + r0;
      *(int4*)&As[row][c8 * 8] = ta[i];
      *(int4*)&Bs[row][c8 * 8] = tb[i];
    }
    __syncthreads();
#pragma unroll
    for (int kk = 0; kk < 2; kk++) {
      short8 af[4], bfr[4];
#pragma unroll
      for (int m = 0; m < 4; m++)
        af[m] = *(const short8*)&As[wr * 64 + m * 16 + lq][kk * 32 + lk * 8];
#pragma unroll
      for (int n = 0; n < 4; n++)
        bfr[n] = *(const short8*)&Bs[wc * 64 + n * 16 + lq][kk * 32 + lk * 8];
#pragma unroll
      for (int m = 0; m < 4; m++)
#pragma unroll
        for (int n = 0; n < 4; n++)
          acc[m][n] = __builtin_amdgcn_mfma_f32_16x16x32_bf16(af[m], bfr[n], acc[m][n], 0, 0, 0);
    }
    __syncthreads();
  }
#pragma unroll
  for (int n = 0; n < 4; n++) {
    int el = n0 + wc * 64 + n * 16 + lq;
    float bi = bo[el];
#pragma unroll
    for (int m = 0; m < 4; m++) {
      int row = m0 + wr * 64 + m * 16 + lk * 4;
#pragma unroll
      for (int r = 0; r < 4; r++)
        out[(size_t)(row + r) * DMODEL + el] = acc[m][n][r] + bi;
    }
  }
}

extern "C" void kernel_launch(void* const* d_in, const int* in_sizes, int n_in,
                              void* d_out, int out_size, void* d_ws, size_t ws_size,
                              hipStream_t stream) {
  const float* x  = (const float*)d_in[0];
  // d_in[1] = mask (causal tril) — computed analytically, not read
  const float* Wq = (const float*)d_in[2];
  const float* bq = (const float*)d_in[3];
  const float* Wk = (const float*)d_in[4];
  const float* bk = (const float*)d_in[5];
  const float* Wv = (const float*)d_in[6];
  const float* bv = (const float*)d_in[7];
  const float* Wo = (const float*)d_in[8];
  const float* bo = (const float*)d_in[9];
  float* out = (float*)d_out;
  char* ws = (char*)d_ws;

  unsigned short* xb  = (unsigned short*)(ws + XB_OFF);   // also attn output O
  unsigned short* wqb = (unsigned short*)(ws + WQ_OFF);   // also Wo bf16 later
  unsigned short* wkb = (unsigned short*)(ws + WK_OFF);
  unsigned short* wvb = (unsigned short*)(ws + WV_OFF);
  unsigned short* qr  = (unsigned short*)(ws + Q_OFF);
  unsigned short* kr  = (unsigned short*)(ws + K_OFF);
  unsigned short* vt  = (unsigned short*)(ws + VT_OFF);
  float* ct = (float*)(ws + COS_OFF);
  float* st = (float*)(ws + SIN_OFF);

  // 1. convert inputs to bf16
  k_cvt<<<(MROWS * DMODEL / 4 + 255) / 256, 256, 0, stream>>>(x, xb, MROWS * DMODEL / 4);
  k_cvt<<<(DMODEL * DMODEL / 4 + 255) / 256, 256, 0, stream>>>(Wq, wqb, DMODEL * DMODEL / 4);
  k_cvt<<<(DMODEL * DMODEL / 4 + 255) / 256, 256, 0, stream>>>(Wk, wkb, DMODEL * DMODEL / 4);
  k_cvt<<<(DMODEL * DMODEL / 4 + 255) / 256, 256, 0, stream>>>(Wv, wvb, DMODEL * DMODEL / 4);
  // 2. RoPE tables
  k_rope_table<<<(S_LEN * 64 + 255) / 256, 256, 0, stream>>>(ct, st);
  // 3. fused QKV projection (writes qr/kr as (bh,s,d), vt as (bh,d,s))
  k_gemm_qkv<<<dim3(MROWS / 128, 6144 / 128), 256, 0, stream>>>(
      xb, wqb, wkb, wvb, bq, bk, bv, qr, kr, vt);
  // 4. Wo -> bf16 (reuses Wq slot, now free)
  k_cvt<<<(DMODEL * DMODEL / 4 + 255) / 256, 256, 0, stream>>>(Wo, wqb, DMODEL * DMODEL / 4);
  // 5. in-place RoPE; Q additionally scaled by 1/sqrt(HDIM)
  k_rope<<<(BHTOT * S_LEN * 8) / 256, 256, 0, stream>>>(qr, ct, st, 0.08838834764831843f, 3);
  k_rope<<<(BHTOT * S_LEN * 4) / 256, 256, 0, stream>>>(kr, ct, st, 1.0f, 2);
  // 6. causal flash attention -> O (b,s,e) bf16 into xb slot
  k_attn<<<dim3(BHTOT, S_LEN / 64), 256, 0, stream>>>(qr, kr, vt, xb);
  // 7. output projection -> fp32 out
  k_gemm_out<<<dim3(MROWS / 128, DMODEL / 128), 256, 0, stream>>>(xb, wqb, bo, out);
}

// Round 2
// 368.416 us; speedup vs baseline: 1.0220x; 1.0220x over previous
//
#include <hip/hip_runtime.h>
#include <stdint.h>
#include <math.h>

typedef short short8 __attribute__((ext_vector_type(8)));
typedef float f32x4 __attribute__((ext_vector_type(4)));

// Problem constants
#define S_LEN   2048
#define DMODEL  2048
#define NHEADS  16
#define HDIM    128
#define NBATCH  2
#define BHTOT   32      // NBATCH*NHEADS
#define MROWS   4096    // NBATCH*S_LEN

// Workspace byte offsets (total ~89 MB)
#define XB_OFF   ((size_t)0)          // 4096*2048 bf16 = 16MB   (x bf16; reused as attn-output O)
#define WQ_OFF   ((size_t)16777216)   // 2048*2048 bf16 = 8MB    (Wq bf16; reused for Wo bf16)
#define WK_OFF   ((size_t)25165824)
#define WV_OFF   ((size_t)33554432)
#define Q_OFF    ((size_t)41943040)   // (bh,s,d) bf16 16MB
#define K_OFF    ((size_t)58720256)   // (bh,s,d) bf16 16MB
#define VT_OFF   ((size_t)75497472)   // (bh,d,s) bf16 16MB  (V pre-transposed)
#define COS_OFF  ((size_t)92274688)   // 2048*64 f32
#define SIN_OFF  ((size_t)92798976)   // 2048*64 f32

__device__ __forceinline__ unsigned short f2bf(float f) {
  unsigned int u = __float_as_uint(f);
  unsigned int r = (u + 0x7FFFu + ((u >> 16) & 1u)) >> 16;  // RTNE
  return (unsigned short)r;
}
__device__ __forceinline__ float bf2f(unsigned short b) {
  return __uint_as_float(((unsigned int)b) << 16);
}

// ---------------- fp32 -> bf16 convert (vectorized) ----------------
__global__ __launch_bounds__(256) void k_cvt(const float* __restrict__ src,
                                             unsigned short* __restrict__ dst, int n4) {
  int i = blockIdx.x * 256 + threadIdx.x;
  if (i >= n4) return;
  float4 v = ((const float4*)src)[i];
  ushort4 o;
  o.x = f2bf(v.x); o.y = f2bf(v.y); o.z = f2bf(v.z); o.w = f2bf(v.w);
  ((ushort4*)dst)[i] = o;
}

// ---------------- RoPE cos/sin table: [s][j], j<64 ----------------
__global__ __launch_bounds__(256) void k_rope_table(float* __restrict__ ct,
                                                    float* __restrict__ st) {
  int i = blockIdx.x * 256 + threadIdx.x;   // 2048*64 total
  if (i >= S_LEN * 64) return;
  int s = i >> 6, j = i & 63;
  float inv = expf(-(float)(2 * j) * (9.210340371976184f / 128.0f));
  float ang = (float)s * inv;
  ct[i] = cosf(ang);
  st[i] = sinf(ang);
}

// ---------------- in-place RoPE on (bh, s, 128) bf16 ----------------
__global__ __launch_bounds__(256) void k_rope(unsigned short* __restrict__ t,
                                              const float* __restrict__ ct,
                                              const float* __restrict__ st,
                                              float scale, int shift) {
  int id = blockIdx.x * 256 + threadIdx.x;
  int row = id >> shift;               // bh*2048 + s
  int c = id & ((1 << shift) - 1);
  int s = row & (S_LEN - 1);
  unsigned short* base = t + (size_t)row * HDIM;
  if (c < 4) {
    short8 v1 = *(short8*)(base + c * 8);
    short8 v2 = *(short8*)(base + c * 8 + 32);
    int j0 = c * 8;
    const float* cb = ct + s * 64;
    const float* sb = st + s * 64;
    short8 o1, o2;
#pragma unroll
    for (int i = 0; i < 8; i++) {
      float x1 = bf2f((unsigned short)v1[i]);
      float x2 = bf2f((unsigned short)v2[i]);
      float c1 = cb[j0 + i],      s1 = sb[j0 + i];
      float c2 = cb[j0 + 32 + i], s2 = sb[j0 + 32 + i];
      o1[i] = (short)f2bf((x1 * c1 - x2 * s1) * scale);
      o2[i] = (short)f2bf((x2 * c2 + x1 * s2) * scale);
    }
    *(short8*)(base + c * 8) = o1;
    *(short8*)(base + c * 8 + 32) = o2;
  } else {
    int cc = 8 + (c - 4) * 2;   // passthrough chunks 8..15, scaled (Q only)
    short8 v1 = *(short8*)(base + cc * 8);
    short8 v2 = *(short8*)(base + cc * 8 + 8);
    short8 o1, o2;
#pragma unroll
    for (int i = 0; i < 8; i++) {
      o1[i] = (short)f2bf(bf2f((unsigned short)v1[i]) * scale);
      o2[i] = (short)f2bf(bf2f((unsigned short)v2[i]) * scale);
    }
    *(short8*)(base + cc * 8) = o1;
    *(short8*)(base + cc * 8 + 8) = o2;
  }
}

// ---------------- fused QKV projection GEMM ----------------
__global__ __launch_bounds__(256) void k_gemm_qkv(
    const unsigned short* __restrict__ xb,
    const unsigned short* __restrict__ wqb, const unsigned short* __restrict__ wkb,
    const unsigned short* __restrict__ wvb,
    const float* __restrict__ bq, const float* __restrict__ bk, const float* __restrict__ bv,
    unsigned short* __restrict__ qr, unsigned short* __restrict__ kr,
    unsigned short* __restrict__ vt) {
  __shared__ unsigned short As[128][72];   // +8 pad -> frag reads 2-way (free)
  __shared__ unsigned short Bs[128][72];
  int m0 = blockIdx.x * 128;
  int n0g = blockIdx.y * 128;              // 0..6143
  int wsel = n0g >> 11;                    // 0=Q 1=K 2=V
  int nw0 = n0g & (DMODEL - 1);
  const unsigned short* W = (wsel == 0) ? wqb : (wsel == 1 ? wkb : wvb);
  const float* bias = (wsel == 0) ? bq : (wsel == 1 ? bk : bv);
  int tid = threadIdx.x, lane = tid & 63, wid = tid >> 6;
  int wr = wid >> 1, wc = wid & 1;
  int lq = lane & 15, lk = lane >> 4;
  int r0 = tid >> 3, c8 = tid & 7;

  f32x4 acc[4][4];
#pragma unroll
  for (int m = 0; m < 4; m++)
#pragma unroll
    for (int n = 0; n < 4; n++) { acc[m][n][0]=0.f; acc[m][n][1]=0.f; acc[m][n][2]=0.f; acc[m][n][3]=0.f; }

  for (int k0 = 0; k0 < DMODEL; k0 += 64) {
    int4 ta[4], tb[4];
#pragma unroll
    for (int i = 0; i < 4; i++) {
      int row = i * 32 + r0;
      ta[i] = *(const int4*)(xb + (size_t)(m0 + row) * DMODEL + k0 + c8 * 8);
      tb[i] = *(const int4*)(W  + (size_t)(nw0 + row) * DMODEL + k0 + c8 * 8);
    }
#pragma unroll
    for (int i = 0; i < 4; i++) {
      int row = i * 32 + r0;
      *(int4*)&As[row][c8 * 8] = ta[i];
      *(int4*)&Bs[row][c8 * 8] = tb[i];
    }
    __syncthreads();
#pragma unroll
    for (int kk = 0; kk < 2; kk++) {
      short8 af[4], bfr[4];
#pragma unroll
      for (int m = 0; m < 4; m++)
        af[m] = *(const short8*)&As[wr * 64 + m * 16 + lq][kk * 32 + lk * 8];
#pragma unroll
      for (int n = 0; n < 4; n++)
        bfr[n] = *(const short8*)&Bs[wc * 64 + n * 16 + lq][kk * 32 + lk * 8];
#pragma unroll
      for (int m = 0; m < 4; m++)
#pragma unroll
        for (int n = 0; n < 4; n++)
          acc[m][n] = __builtin_amdgcn_mfma_f32_16x16x32_bf16(af[m], bfr[n], acc[m][n], 0, 0, 0);
    }
    __syncthreads();
  }

#pragma unroll
  for (int n = 0; n < 4; n++) {
    int el = nw0 + wc * 64 + n * 16 + lq;
    float bi = bias[el];
    int hh = el >> 7, dd = el & 127;
#pragma unroll
    for (int m = 0; m < 4; m++) {
      int sg = m0 + wr * 64 + m * 16 + lk * 4;
      int b = sg >> 11, ss = sg & (S_LEN - 1);
      if (wsel < 2) {
        unsigned short* dst = (wsel == 0 ? qr : kr) +
                              ((size_t)(b * NHEADS + hh) * S_LEN + ss) * HDIM + dd;
#pragma unroll
        for (int r = 0; r < 4; r++) dst[(size_t)r * HDIM] = f2bf(acc[m][n][r] + bi);
      } else {
        ushort4 o;
        o.x = f2bf(acc[m][n][0] + bi); o.y = f2bf(acc[m][n][1] + bi);
        o.z = f2bf(acc[m][n][2] + bi); o.w = f2bf(acc[m][n][3] + bi);
        *(ushort4*)(vt + ((size_t)(b * NHEADS + hh) * HDIM + dd) * S_LEN + ss) = o;
      }
    }
  }
}

// ---------------- causal flash attention (fold-balanced) ----------------
// Q pre-scaled by 1/sqrt(128). grid = (bh=32, fold=16).
// Each block processes q-tiles {fold, 31-fold}: (fold+1)+(32-fold)=33 KV steps
// for EVERY block -> perfectly balanced grid, all 512 blocks co-resident
// (45KB LDS -> 3 blocks/CU = 768 slots), no dispatch-order tail.
__global__ __launch_bounds__(256) void k_attn(
    const unsigned short* __restrict__ qr, const unsigned short* __restrict__ kr,
    const unsigned short* __restrict__ vt, unsigned short* __restrict__ ob) {
  __shared__ unsigned short Ks[64][136];    // kv x d (+8 pad)
  __shared__ unsigned short Vs[128][72];    // d x kv (+8 pad)
  __shared__ unsigned short Ps[4][16][72];  // per-wave P round-trip
  int bh = blockIdx.x, fold = blockIdx.y;
  int b = bh >> 4, h = bh & 15;
  int tid = threadIdx.x, lane = tid & 63, w = tid >> 6;
  int lq = lane & 15, lk = lane >> 4;

  for (int half = 0; half < 2; half++) {
    int qt = (half == 0) ? fold : (31 - fold);
    int q0 = qt * 64;

    // Q fragments (registers)
    const unsigned short* qbase =
        qr + ((size_t)bh * S_LEN + q0 + w * 16 + lq) * HDIM + lk * 8;
    short8 qf[4];
#pragma unroll
    for (int ks = 0; ks < 4; ks++) qf[ks] = *(const short8*)(qbase + ks * 32);

    f32x4 acco[8];
#pragma unroll
    for (int nd = 0; nd < 8; nd++) { acco[nd][0]=0.f; acco[nd][1]=0.f; acco[nd][2]=0.f; acco[nd][3]=0.f; }
    float rm[4], rs[4];
#pragma unroll
    for (int r = 0; r < 4; r++) { rm[r] = -3.0e38f; rs[r] = 0.f; }

    for (int t = 0; t <= qt; t++) {
      int kv0 = t * 64;
#pragma unroll
      for (int i = 0; i < 4; i++) {
        int row = i * 16 + (tid >> 4), col = (tid & 15) * 8;
        *(int4*)&Ks[row][col] =
            *(const int4*)(kr + ((size_t)bh * S_LEN + kv0 + row) * HDIM + col);
      }
#pragma unroll
      for (int i = 0; i < 4; i++) {
        int row = i * 32 + (tid >> 3), col = (tid & 7) * 8;
        *(int4*)&Vs[row][col] =
            *(const int4*)(vt + ((size_t)bh * HDIM + row) * S_LEN + kv0 + col);
      }
      __syncthreads();

      // S = Q K^T (16x64 per wave)
      f32x4 sacc[4];
#pragma unroll
      for (int n = 0; n < 4; n++) { sacc[n][0]=0.f; sacc[n][1]=0.f; sacc[n][2]=0.f; sacc[n][3]=0.f; }
#pragma unroll
      for (int ks = 0; ks < 4; ks++) {
#pragma unroll
        for (int n = 0; n < 4; n++) {
          short8 kf = *(const short8*)&Ks[n * 16 + lq][ks * 32 + lk * 8];
          sacc[n] = __builtin_amdgcn_mfma_f32_16x16x32_bf16(qf[ks], kf, sacc[n], 0, 0, 0);
        }
      }
      // causal mask on diagonal tile
      if (t == qt) {
#pragma unroll
        for (int n = 0; n < 4; n++)
#pragma unroll
          for (int r = 0; r < 4; r++) {
            int qrow = q0 + w * 16 + lk * 4 + r;
            int kvc = kv0 + n * 16 + lq;
            if (kvc > qrow) sacc[n][r] = -3.0e38f;
          }
      }
      // online softmax
      float pscale[4];
#pragma unroll
      for (int r = 0; r < 4; r++) {
        float mx = fmaxf(fmaxf(sacc[0][r], sacc[1][r]), fmaxf(sacc[2][r], sacc[3][r]));
        mx = fmaxf(mx, __shfl_xor(mx, 1, 64));
        mx = fmaxf(mx, __shfl_xor(mx, 2, 64));
        mx = fmaxf(mx, __shfl_xor(mx, 4, 64));
        mx = fmaxf(mx, __shfl_xor(mx, 8, 64));
        float mnew = fmaxf(rm[r], mx);
        float corr = __expf(rm[r] - mnew);
        rm[r] = mnew;
        float psum = 0.f;
#pragma unroll
        for (int n = 0; n < 4; n++) {
          float p = __expf(sacc[n][r] - mnew);
          sacc[n][r] = p;
          psum += p;
        }
        psum += __shfl_xor(psum, 1, 64);
        psum += __shfl_xor(psum, 2, 64);
        psum += __shfl_xor(psum, 4, 64);
        psum += __shfl_xor(psum, 8, 64);
        rs[r] = rs[r] * corr + psum;
        pscale[r] = corr;
      }
#pragma unroll
      for (int nd = 0; nd < 8; nd++)
#pragma unroll
        for (int r = 0; r < 4; r++) acco[nd][r] *= pscale[r];

      // P -> bf16 -> LDS (accumulator layout -> A-frag layout)
#pragma unroll
      for (int n = 0; n < 4; n++)
#pragma unroll
        for (int r = 0; r < 4; r++)
          Ps[w][lk * 4 + r][n * 16 + lq] = f2bf(sacc[n][r]);

      // PV: O += P @ V
#pragma unroll
      for (int ks = 0; ks < 2; ks++) {
        short8 pa = *(const short8*)&Ps[w][lq][ks * 32 + lk * 8];
#pragma unroll
        for (int nd = 0; nd < 8; nd++) {
          short8 vf = *(const short8*)&Vs[nd * 16 + lq][ks * 32 + lk * 8];
          acco[nd] = __builtin_amdgcn_mfma_f32_16x16x32_bf16(pa, vf, acco[nd], 0, 0, 0);
        }
      }
      __syncthreads();
    }

    // normalize + store O as (b, s, e) bf16
#pragma unroll
    for (int r = 0; r < 4; r++) {
      float inv = 1.0f / rs[r];
      int srow = q0 + w * 16 + lk * 4 + r;
      unsigned short* dst = ob + ((size_t)b * S_LEN + srow) * DMODEL + h * HDIM;
#pragma unroll
      for (int nd = 0; nd < 8; nd++) dst[nd * 16 + lq] = f2bf(acco[nd][r] * inv);
    }
  }
}

// ---------------- output projection GEMM (fp32 out) ----------------
__global__ __launch_bounds__(256) void k_gemm_out(
    const unsigned short* __restrict__ ob, const unsigned short* __restrict__ wob,
    const float* __restrict__ bo, float* __restrict__ out) {
  __shared__ unsigned short As[128][72];
  __shared__ unsigned short Bs[128][72];
  int m0 = blockIdx.x * 128, n0 = blockIdx.y * 128;
  int tid = threadIdx.x, lane = tid & 63, wid = tid >> 6;
  int wr = wid >> 1, wc = wid & 1;
  int lq = lane & 15, lk = lane >> 4;
  int r0 = tid >> 3, c8 = tid & 7;

  f32x4 acc[4][4];
#pragma unroll
  for (int m = 0; m < 4; m++)
#pragma unroll
    for (int n = 0; n < 4; n++) { acc[m][n][0]=0.f; acc[m][n][1]=0.f; acc[m][n][2]=0.f; acc[m][n][3]=0.f; }

  for (int k0 = 0; k0 < DMODEL; k0 += 64) {
    int4 ta[4], tb[4];
#pragma unroll
    for (int i = 0; i < 4; i++) {
      int row = i * 32 + r0;
      ta[i] = *(const int4*)(ob  + (size_t)(m0 + row) * DMODEL + k0 + c8 * 8);
      tb[i] = *(const int4*)(wob + (size_t)(n0 + row) * DMODEL + k0 + c8 * 8);
    }
#pragma unroll
    for (int i = 0; i < 4; i++) {
      int row = i * 32 + r0;
      *(int4*)&As[row][c8 * 8] = ta[i];
      *(int4*)&Bs[row][c8 * 8] = tb[i];
    }
    __syncthreads();
#pragma unroll
    for (int kk = 0; kk < 2; kk++) {
      short8 af[4], bfr[4];
#pragma unroll
      for (int m = 0; m < 4; m++)
        af[m] = *(const short8*)&As[wr * 64 + m * 16 + lq][kk * 32 + lk * 8];
#pragma unroll
      for (int n = 0; n < 4; n++)
        bfr[n] = *(const short8*)&Bs[wc * 64 + n * 16 + lq][kk * 32 + lk * 8];
#pragma unroll
      for (int m = 0; m < 4; m++)
#pragma unroll
        for (int n = 0; n < 4; n++)
          acc[m][n] = __builtin_amdgcn_mfma_f32_16x16x32_bf16(af[m], bfr[n], acc[m][n], 0, 0, 0);
    }
    __syncthreads();
  }
#pragma unroll
  for (int n = 0; n < 4; n++) {
    int el = n0 + wc * 64 + n * 16 + lq;
    float bi = bo[el];
#pragma unroll
    for (int m = 0; m < 4; m++) {
      int row = m0 + wr * 64 + m * 16 + lk * 4;
#pragma unroll
      for (int r = 0; r < 4; r++)
        out[(size_t)(row + r) * DMODEL + el] = acc[m][n][r] + bi;
    }
  }
}

extern "C" void kernel_launch(void* const* d_in, const int* in_sizes, int n_in,
                              void* d_out, int out_size, void* d_ws, size_t ws_size,
                              hipStream_t stream) {
  const float* x  = (const float*)d_in[0];
  const float* Wq = (const float*)d_in[2];
  const float* bq = (const float*)d_in[3];
  const float* Wk = (const float*)d_in[4];
  const float* bk = (const float*)d_in[5];
  const float* Wv = (const float*)d_in[6];
  const float* bv = (const float*)d_in[7];
  const float* Wo = (const float*)d_in[8];
  const float* bo = (const float*)d_in[9];
  float* out = (float*)d_out;
  char* ws = (char*)d_ws;

  unsigned short* xb  = (unsigned short*)(ws + XB_OFF);
  unsigned short* wqb = (unsigned short*)(ws + WQ_OFF);
  unsigned short* wkb = (unsigned short*)(ws + WK_OFF);
  unsigned short* wvb = (unsigned short*)(ws + WV_OFF);
  unsigned short* qr  = (unsigned short*)(ws + Q_OFF);
  unsigned short* kr  = (unsigned short*)(ws + K_OFF);
  unsigned short* vt  = (unsigned short*)(ws + VT_OFF);
  float* ct = (float*)(ws + COS_OFF);
  float* st = (float*)(ws + SIN_OFF);

  k_cvt<<<(MROWS * DMODEL / 4 + 255) / 256, 256, 0, stream>>>(x, xb, MROWS * DMODEL / 4);
  k_cvt<<<(DMODEL * DMODEL / 4 + 255) / 256, 256, 0, stream>>>(Wq, wqb, DMODEL * DMODEL / 4);
  k_cvt<<<(DMODEL * DMODEL / 4 + 255) / 256, 256, 0, stream>>>(Wk, wkb, DMODEL * DMODEL / 4);
  k_cvt<<<(DMODEL * DMODEL / 4 + 255) / 256, 256, 0, stream>>>(Wv, wvb, DMODEL * DMODEL / 4);
  k_rope_table<<<(S_LEN * 64 + 255) / 256, 256, 0, stream>>>(ct, st);
  k_gemm_qkv<<<dim3(MROWS / 128, 6144 / 128), 256, 0, stream>>>(
      xb, wqb, wkb, wvb, bq, bk, bv, qr, kr, vt);
  k_cvt<<<(DMODEL * DMODEL / 4 + 255) / 256, 256, 0, stream>>>(Wo, wqb, DMODEL * DMODEL / 4);
  k_rope<<<(BHTOT * S_LEN * 8) / 256, 256, 0, stream>>>(qr, ct, st, 0.08838834764831843f, 3);
  k_rope<<<(BHTOT * S_LEN * 4) / 256, 256, 0, stream>>>(kr, ct, st, 1.0f, 2);
  // fold-balanced causal flash attention
  k_attn<<<dim3(BHTOT, 16), 256, 0, stream>>>(qr, kr, vt, xb);
  k_gemm_out<<<dim3(MROWS / 128, DMODEL / 128), 256, 0, stream>>>(xb, wqb, bo, out);
}